// Round 13
// baseline (142.661 us; speedup 1.0000x reference)
//
#include <hip/hip_runtime.h>
#include <hip/hip_bf16.h>
#include <math.h>

// Problem constants
#define B_ 256
#define M_ 512
#define D_ 768
#define H_ 8
#define DH_ 96
#define C_ 768

typedef float  f32x4_t __attribute__((ext_vector_type(4)));
typedef short  s16x8   __attribute__((ext_vector_type(8)));
typedef unsigned short u16;

__device__ __forceinline__ u16 cvt_bf16(float f) {
    __hip_bfloat16 h = __float2bfloat16(f);     // HW cvt path (RNE)
    union { __hip_bfloat16 h; u16 u; } v; v.h = h;
    return v.u;
}
__device__ __forceinline__ float bf16_f32(u16 h) {
    union { unsigned int u; float f; } v; v.u = ((unsigned int)h) << 16;
    return v.f;
}

#define ACC_INIT {{0,0,0,0},{0,0,0,0},{0,0,0,0},{0,0,0,0}}
#define ACC_INIT8 {{0,0,0,0},{0,0,0,0},{0,0,0,0},{0,0,0,0},{0,0,0,0},{0,0,0,0},{0,0,0,0},{0,0,0,0}}
#define SCALE_ 0.10206207261596577f   // 1/sqrt(96)

// ---------------------------------------------------------------------------
// 64x64 bf16 MFMA GEMM core (proven R5-R12), software-pipelined.
// tile = A(64xK) @ B(64xK)^T, both K-major bf16.
// ---------------------------------------------------------------------------
template<int BK>
__device__ __forceinline__ void mm64b(
    const u16* __restrict__ A, int lda, const u16* __restrict__ B, int ldb,
    int ksteps, int bRowClamp, u16* lA, u16* lB, f32x4_t* acc, int nfrag)
{
    constexpr int NL = BK / 32;
    const int t = threadIdx.x;
    const int srow = t >> 2, kq = t & 3;
    const int l = t & 63, w = t >> 6;
    const int brow = srow < bRowClamp ? srow : bRowClamp;

    s16x8 va[NL], vb[NL];
    #pragma unroll
    for (int c = 0; c < NL; ++c) {                 // preload k-step 0
        const int ko = (kq * NL + c) * 8;
        va[c] = *reinterpret_cast<const s16x8*>(A + (size_t)srow * lda + ko);
        vb[c] = *reinterpret_cast<const s16x8*>(B + (size_t)brow * ldb + ko);
    }

    for (int ks = 0; ks < ksteps; ++ks) {
        __syncthreads();                           // prev iter's frag reads done
        #pragma unroll
        for (int c = 0; c < NL; ++c) {
            const int kb = kq * NL + c;
            *reinterpret_cast<s16x8*>(lA + (kb * 64 + srow) * 8) = va[c];
            *reinterpret_cast<s16x8*>(lB + (kb * 64 + srow) * 8) = vb[c];
        }
        __syncthreads();
        if (ks + 1 < ksteps) {                     // prefetch: hides under MFMAs
            #pragma unroll
            for (int c = 0; c < NL; ++c) {
                const int ko = (ks + 1) * BK + (kq * NL + c) * 8;
                va[c] = *reinterpret_cast<const s16x8*>(A + (size_t)srow * lda + ko);
                vb[c] = *reinterpret_cast<const s16x8*>(B + (size_t)brow * ldb + ko);
            }
        }
        #pragma unroll
        for (int ksub = 0; ksub < NL; ++ksub) {
            const int kb = (l >> 4) + ksub * 4;
            s16x8 af = *reinterpret_cast<const s16x8*>(lA + (kb * 64 + w * 16 + (l & 15)) * 8);
            #pragma unroll
            for (int nb = 0; nb < 4; ++nb) {
                if (nb < nfrag) {
                    s16x8 bf = *reinterpret_cast<const s16x8*>(lB + (kb * 64 + nb * 16 + (l & 15)) * 8);
                    acc[nb] = __builtin_amdgcn_mfma_f32_16x16x32_bf16(af, bf, acc[nb], 0, 0, 0);
                }
            }
        }
    }
}

// ---------------------------------------------------------------------------
// 64x128 bf16 MFMA GEMM core: 2x wider B-tile -> 16 MFMAs per wave per k-step
// against 6 staging ops (vs 8:4 for 64x64). acc has 8 fragments.
// B tile always full 128 rows (callers guarantee in-bounds).
// ---------------------------------------------------------------------------
template<int BK>
__device__ __forceinline__ void mm64x128(
    const u16* __restrict__ A, int lda, const u16* __restrict__ B, int ldb,
    int ksteps, u16* lA, u16* lB, f32x4_t* acc)
{
    constexpr int NL  = BK / 32;     // A chunks per thread (64 rows, 4 thr/row)
    constexpr int NLB = BK / 16;     // B chunks per thread (128 rows, 2 thr/row)
    const int t = threadIdx.x;
    const int arow = t >> 2, akq = t & 3;
    const int brow = t >> 1, bkq = t & 1;
    const int l = t & 63, w = t >> 6;

    s16x8 va[NL], vb[NLB];
    #pragma unroll
    for (int c = 0; c < NL; ++c)
        va[c] = *reinterpret_cast<const s16x8*>(A + (size_t)arow * lda + (akq * NL + c) * 8);
    #pragma unroll
    for (int c = 0; c < NLB; ++c)
        vb[c] = *reinterpret_cast<const s16x8*>(B + (size_t)brow * ldb + (bkq * NLB + c) * 8);

    for (int ks = 0; ks < ksteps; ++ks) {
        __syncthreads();
        #pragma unroll
        for (int c = 0; c < NL; ++c) {
            const int kb = akq * NL + c;
            *reinterpret_cast<s16x8*>(lA + (kb * 64 + arow) * 8) = va[c];
        }
        #pragma unroll
        for (int c = 0; c < NLB; ++c) {
            const int kb = bkq * NLB + c;
            *reinterpret_cast<s16x8*>(lB + (kb * 128 + brow) * 8) = vb[c];
        }
        __syncthreads();
        if (ks + 1 < ksteps) {
            #pragma unroll
            for (int c = 0; c < NL; ++c)
                va[c] = *reinterpret_cast<const s16x8*>(A + (size_t)arow * lda + (ks + 1) * BK + (akq * NL + c) * 8);
            #pragma unroll
            for (int c = 0; c < NLB; ++c)
                vb[c] = *reinterpret_cast<const s16x8*>(B + (size_t)brow * ldb + (ks + 1) * BK + (bkq * NLB + c) * 8);
        }
        #pragma unroll
        for (int ksub = 0; ksub < NL; ++ksub) {
            const int kb = (l >> 4) + ksub * 4;
            s16x8 af = *reinterpret_cast<const s16x8*>(lA + (kb * 64 + w * 16 + (l & 15)) * 8);
            #pragma unroll
            for (int nb = 0; nb < 8; ++nb) {
                s16x8 bf = *reinterpret_cast<const s16x8*>(lB + (kb * 128 + nb * 16 + (l & 15)) * 8);
                acc[nb] = __builtin_amdgcn_mfma_f32_16x16x32_bf16(af, bf, acc[nb], 0, 0, 0);
            }
        }
    }
}

// C/D layout: col = lane&15, row = (lane>>4)*4 + reg (within wave's 16-row slice).
__device__ __forceinline__ void epilogue_f32(
    const f32x4_t* acc, float* out, int ldo, int m0, int n0,
    const float* bias, int act, int nfrag)
{
    const int t = threadIdx.x, l = t & 63, w = t >> 6;
    const int mbase = m0 + w * 16 + (l >> 4) * 4;
    #pragma unroll
    for (int nb = 0; nb < 8; ++nb) {
        if (nb >= nfrag) break;
        const int col = n0 + nb * 16 + (l & 15);
        const float bv = bias ? bias[col] : 0.0f;
        #pragma unroll
        for (int r = 0; r < 4; ++r) {
            float v = acc[nb][r] + bv;
            if (act) v = 1.0f / (1.0f + expf(-v));
            out[(size_t)(mbase + r) * ldo + col] = v;
        }
    }
}

__device__ __forceinline__ void epilogue_bf16(
    const f32x4_t* acc, u16* out, int ldo, int m0, int n0,
    const float* bias, int nfrag)
{
    const int t = threadIdx.x, l = t & 63, w = t >> 6;
    const int mbase = m0 + w * 16 + (l >> 4) * 4;
    #pragma unroll
    for (int nb = 0; nb < 8; ++nb) {
        if (nb >= nfrag) break;
        const int col = n0 + nb * 16 + (l & 15);
        const float bv = bias ? bias[col] : 0.0f;
        #pragma unroll
        for (int r = 0; r < 4; ++r)
            out[(size_t)(mbase + r) * ldo + col] = cvt_bf16(acc[nb][r] + bv);
    }
}

// ---------------------------------------------------------------------------
// L1 conv (2328 blocks): f32->bf16 conversions (2304) + vg/gc GEMV (24).
// ---------------------------------------------------------------------------
__global__ __launch_bounds__(256) void conv_kernel(
    const float* __restrict__ mem, const float* __restrict__ cs,
    const float* __restrict__ ipw, const float* __restrict__ rw,
    const float* __restrict__ www, const float* __restrict__ ew,
    const float* __restrict__ outw, const float* __restrict__ outb,
    const float* __restrict__ ugw, const float* __restrict__ ugb,
    const float* __restrict__ fgw, const float* __restrict__ fgb,
    u16* __restrict__ memb, u16* __restrict__ csb, u16* __restrict__ ipwb,
    u16* __restrict__ rwb, u16* __restrict__ wwwb, u16* __restrict__ ewb,
    u16* __restrict__ outwb, float* __restrict__ vg, float* __restrict__ gc)
{
    __shared__ float sred[256];
    const int bid = blockIdx.x, t = threadIdx.x;

    if (bid < 2304) {
        const float* src; u16* dst; int base;
        if      (bid < 192)  { src = mem;  dst = memb;  base = bid; }
        else if (bid < 288)  { src = cs;   dst = csb;   base = bid - 192; }
        else if (bid < 1152) { src = ipw;  dst = ipwb;  base = bid - 288; }
        else if (bid < 1440) { src = rw;   dst = rwb;   base = bid - 1152; }
        else if (bid < 1728) { src = www;  dst = wwwb;  base = bid - 1440; }
        else if (bid < 2016) { src = ew;   dst = ewb;   base = bid - 1728; }
        else                 { src = outw; dst = outwb; base = bid - 2016; }
        const size_t i = ((size_t)base * 256 + t) * 8;
        float4 x = *reinterpret_cast<const float4*>(src + i);
        float4 y = *reinterpret_cast<const float4*>(src + i + 4);
        s16x8 o;
        o[0]=cvt_bf16(x.x); o[1]=cvt_bf16(x.y); o[2]=cvt_bf16(x.z); o[3]=cvt_bf16(x.w);
        o[4]=cvt_bf16(y.x); o[5]=cvt_bf16(y.y); o[6]=cvt_bf16(y.z); o[7]=cvt_bf16(y.w);
        *reinterpret_cast<s16x8*>(dst + i) = o;
    } else {
        const int lid = bid - 2304;
        const int v = lid / 12, kt = lid % 12;
        const float* gw = v == 0 ? ugw : fgw;
        const int c = t & 63, g = t >> 6;
        const int col = kt * 64 + c;
        float acc = 0.f;
        #pragma unroll 4
        for (int i = 0; i < 192; ++i) {
            const int row = g * 192 + i;
            acc += outw[(size_t)row * 768 + col] * gw[768 + row];
        }
        sred[t] = acc;
        __syncthreads();
        if (g == 0)
            vg[v * 768 + col] = sred[c] + sred[64 + c] + sred[128 + c] + sred[192 + c];
        if (kt == 0) {
            __syncthreads();
            float cp = outb[t] * gw[768 + t] + outb[t + 256] * gw[768 + t + 256]
                     + outb[t + 512] * gw[768 + t + 512];
            sred[t] = cp; __syncthreads();
            #pragma unroll
            for (int off = 128; off > 0; off >>= 1) {
                if (t < off) sred[t] += sred[t + off];
                __syncthreads();
            }
            if (t == 0) gc[v] = sred[0] + (v == 0 ? ugb[0] : fgb[0]);
        }
    }
}

// ---------------------------------------------------------------------------
// L2 stage1 (168 blocks, 64x128 tiles): kh+vhT (96), read keys (24),
// write keys (24), erase (24).
// ---------------------------------------------------------------------------
__global__ __launch_bounds__(256) void stage1_kernel(
    const u16* __restrict__ memb, const u16* __restrict__ csb,
    const u16* __restrict__ ipwb, const float* __restrict__ ipb,
    const u16* __restrict__ rwb, const float* __restrict__ rb,
    const u16* __restrict__ wwwb, const float* __restrict__ ww_b,
    const u16* __restrict__ ewb, const float* __restrict__ eb,
    u16* __restrict__ khb, u16* __restrict__ vhT,
    u16* __restrict__ rwkeysb, float* __restrict__ erase)
{
    __shared__ u16 lA[4096], lB[8192];
    f32x4_t acc[8] = ACC_INIT8;
    const int bid = blockIdx.x;
    if (bid < 96) {
        const int mt = bid / 12, nt = bid % 12;
        mm64x128<64>(memb + (size_t)mt * 64 * 768, 768,
                     ipwb + (size_t)768 * 768 + (size_t)nt * 128 * 768, 768,
                     12, lA, lB, acc);
        const int t = threadIdx.x, l = t & 63, w = t >> 6;
        const int mbase = mt * 64 + w * 16 + (l >> 4) * 4;
        if (nt < 6) {
            #pragma unroll
            for (int nb = 0; nb < 8; ++nb) {
                const int col = nt * 128 + nb * 16 + (l & 15);
                const float bv = ipb[768 + col];
                #pragma unroll
                for (int r = 0; r < 4; ++r)
                    khb[(size_t)(mbase + r) * 768 + col] = cvt_bf16(acc[nb][r] + bv);
            }
        } else {
            #pragma unroll
            for (int nb = 0; nb < 8; ++nb) {
                const int cg = (nt - 6) * 128 + nb * 16 + (l & 15);   // 0..767
                const int h = cg / 96, d = cg % 96;
                const float bv = ipb[1536 + cg];
                u16* dst = vhT + ((size_t)h * 96 + d) * 512;
                #pragma unroll
                for (int r = 0; r < 4; ++r)
                    dst[mbase + r] = cvt_bf16(acc[nb][r] + bv);
            }
        }
    } else if (bid < 120) {
        const int lid = bid - 96, mt = lid / 6, nt = lid % 6;
        mm64x128<64>(csb + (size_t)mt * 64 * 768, 768, rwb + (size_t)nt * 128 * 768, 768,
                     12, lA, lB, acc);
        epilogue_bf16(acc, rwkeysb, 768, mt * 64, nt * 128, rb, 8);
    } else if (bid < 144) {
        const int lid = bid - 120, mt = lid / 6, nt = lid % 6;
        mm64x128<64>(csb + (size_t)mt * 64 * 768, 768, wwwb + (size_t)nt * 128 * 768, 768,
                     12, lA, lB, acc);
        epilogue_bf16(acc, rwkeysb + (size_t)256 * 768, 768, mt * 64, nt * 128, ww_b, 8);
    } else {
        const int lid = bid - 144, mt = lid / 6, nt = lid % 6;
        mm64x128<64>(csb + (size_t)mt * 64 * 768, 768, ewb + (size_t)nt * 128 * 768, 768,
                     12, lA, lB, acc);
        epilogue_f32(acc, erase, 768, mt * 64, nt * 128, eb, 1, 8);
    }
}

// ---------------------------------------------------------------------------
// L3 stage2 (96 blocks): qrw = rwkeys(512x768) @ wq^T + bq -> bf16
// ---------------------------------------------------------------------------
__global__ __launch_bounds__(256) void stage2_kernel(
    const u16* __restrict__ rwkeysb, const u16* __restrict__ ipwb,
    const float* __restrict__ ipb, u16* __restrict__ qrwb)
{
    __shared__ u16 lA[4096], lB[4096];
    f32x4_t acc[4] = ACC_INIT;
    const int mt = blockIdx.x / 12, nt = blockIdx.x % 12;
    mm64b<64>(rwkeysb + (size_t)mt * 64 * 768, 768, ipwb + (size_t)nt * 64 * 768, 768,
              12, 63, lA, lB, acc, 4);
    epilogue_bf16(acc, qrwb, 768, mt * 64, nt * 64, ipb, 4);
}

// ---------------------------------------------------------------------------
// L4 scores (grid (32,8), 64x128 tiles): E[h][q][m] = exp(min(q.k*scale,30))
// ---------------------------------------------------------------------------
__global__ __launch_bounds__(256) void scores_kernel(
    const u16* __restrict__ qrwb, const u16* __restrict__ khb, u16* __restrict__ E)
{
    __shared__ u16 lA[2048], lB[4096];
    f32x4_t acc[8] = ACC_INIT8;
    const int h = blockIdx.y;
    const int mt = blockIdx.x >> 2, nt = blockIdx.x & 3;
    mm64x128<32>(qrwb + (size_t)mt * 64 * 768 + h * 96, 768,
                 khb + (size_t)nt * 128 * 768 + h * 96, 768, 3, lA, lB, acc);
    const int t = threadIdx.x, l = t & 63, w = t >> 6;
    const int mbase = mt * 64 + w * 16 + (l >> 4) * 4;     // q
    #pragma unroll
    for (int nb = 0; nb < 8; ++nb) {
        const int col = nt * 128 + nb * 16 + (l & 15);      // m
        #pragma unroll
        for (int r = 0; r < 4; ++r) {
            const float e = expf(fminf(acc[nb][r] * SCALE_, 30.0f));
            E[((size_t)h * 512 + mbase + r) * 512 + col] = cvt_bf16(e);
        }
    }
}

// ---------------------------------------------------------------------------
// L5 PV (grid (4,2,8)): ctx = (E_rows/rowsum) @ vhT^T -> ctxb bf16.
// ---------------------------------------------------------------------------
__global__ __launch_bounds__(256) void pv_kernel(
    const u16* __restrict__ E, const u16* __restrict__ vhT, u16* __restrict__ ctxb)
{
    __shared__ u16 lA[4096], lB[4096];
    __shared__ float rinv[64];
    f32x4_t acc[4] = ACC_INIT;
    const int h = blockIdx.z, mt = blockIdx.x, nt = blockIdx.y;
    const int n0 = nt * 64;
    const int nfrag = nt == 0 ? 4 : 2;
    const int bclamp = nt == 0 ? 63 : 31;

    const u16* A  = E + ((size_t)h * 512 + mt * 64) * 512;
    const u16* Bv = vhT + ((size_t)h * 96 + n0) * 512;

    const int t = threadIdx.x;
    const int srow = t >> 2, kq = t & 3;
    const int l = t & 63, w = t >> 6;
    const int brow = srow < bclamp ? srow : bclamp;

    s16x8 va[2], vb[2];
    #pragma unroll
    for (int c = 0; c < 2; ++c) {                  // preload ks=0
        const int ko = (kq * 2 + c) * 8;
        va[c] = *reinterpret_cast<const s16x8*>(A + (size_t)srow * 512 + ko);
        vb[c] = *reinterpret_cast<const s16x8*>(Bv + (size_t)brow * 512 + ko);
    }

    float rs = 0.f;
    for (int ks = 0; ks < 8; ++ks) {
        __syncthreads();
        #pragma unroll
        for (int c = 0; c < 2; ++c) {
            const int kb = kq * 2 + c;
            *reinterpret_cast<s16x8*>(lA + (kb * 64 + srow) * 8) = va[c];
            *reinterpret_cast<s16x8*>(lB + (kb * 64 + srow) * 8) = vb[c];
        }
        #pragma unroll
        for (int c = 0; c < 2; ++c)                // row-sum on staged values
            #pragma unroll
            for (int j = 0; j < 8; ++j)
                rs += bf16_f32((u16)va[c][j]);
        __syncthreads();
        if (ks + 1 < 8) {                          // prefetch hides under MFMAs
            #pragma unroll
            for (int c = 0; c < 2; ++c) {
                const int ko = (ks + 1) * 64 + (kq * 2 + c) * 8;
                va[c] = *reinterpret_cast<const s16x8*>(A + (size_t)srow * 512 + ko);
                vb[c] = *reinterpret_cast<const s16x8*>(Bv + (size_t)brow * 512 + ko);
            }
        }
        #pragma unroll
        for (int ksub = 0; ksub < 2; ++ksub) {
            const int kb = (l >> 4) + ksub * 4;
            s16x8 af = *reinterpret_cast<const s16x8*>(lA + (kb * 64 + w * 16 + (l & 15)) * 8);
            #pragma unroll
            for (int nb = 0; nb < 4; ++nb) {
                if (nb < nfrag) {
                    s16x8 bf = *reinterpret_cast<const s16x8*>(lB + (kb * 64 + nb * 16 + (l & 15)) * 8);
                    acc[nb] = __builtin_amdgcn_mfma_f32_16x16x32_bf16(af, bf, acc[nb], 0, 0, 0);
                }
            }
        }
    }
    rs += __shfl_xor(rs, 1);
    rs += __shfl_xor(rs, 2);
    if (kq == 0) rinv[srow] = 1.0f / rs;
    __syncthreads();

    const int mbase = w * 16 + (l >> 4) * 4;
    #pragma unroll
    for (int nb = 0; nb < 4; ++nb) {
        if (nb >= nfrag) break;
        const int col = n0 + nb * 16 + (l & 15);
        #pragma unroll
        for (int r = 0; r < 4; ++r) {
            const float v = acc[nb][r] * rinv[mbase + r];
            ctxb[(size_t)(mt * 64 + mbase + r) * 768 + h * 96 + col] = cvt_bf16(v);
        }
    }
}

// ---------------------------------------------------------------------------
// L6 gates+ww (512 blocks): [0,256) gates+delta per batch; [256,512) ww per batch.
// ---------------------------------------------------------------------------
__global__ __launch_bounds__(256) void gatesww_kernel(
    const u16* __restrict__ ctxb,
    const float* __restrict__ cs, const float* __restrict__ wdta,
    const float* __restrict__ erase,
    const float* __restrict__ ugw, const float* __restrict__ fgw,
    const float* __restrict__ vg, const float* __restrict__ gc,
    const u16* __restrict__ E,
    float* __restrict__ delta, float* __restrict__ wwb)
{
    const int bid = blockIdx.x, t = threadIdx.x;
    if (bid < 256) {
        const int b = bid;
        __shared__ float red[8];
        float pu = 0.f, pf = 0.f;
        #pragma unroll
        for (int c = 0; c < 3; ++c) {
            const int i = t + c * 256;
            const float cv = cs[(size_t)b * 768 + i];
            const float xv = bf16_f32(ctxb[(size_t)b * 768 + i]);
            pu += cv * ugw[i] + xv * vg[i];
            pf += cv * fgw[i] + xv * vg[768 + i];
        }
        const int w = t >> 6, l = t & 63;
        #pragma unroll
        for (int off = 32; off > 0; off >>= 1) {
            pu += __shfl_xor(pu, off);
            pf += __shfl_xor(pf, off);
        }
        if (l == 0) { red[w] = pu; red[4 + w] = pf; }
        __syncthreads();
        const float ug = 1.0f / (1.0f + expf(-(red[0] + red[1] + red[2] + red[3] + gc[0])));
        const float fg = 1.0f / (1.0f + expf(-(red[4] + red[5] + red[6] + red[7] + gc[1])));
        #pragma unroll
        for (int c = 0; c < 3; ++c) {
            const int i = t + c * 256;
            delta[(size_t)b * 768 + i] = wdta[(size_t)b * 768 + i] * ug
                                       - erase[(size_t)b * 768 + i] * fg;
        }
    } else {
        // ww[b][m] = 0.125 * sum_h E[h][256+b][m] / rowsum(h, 256+b)
        const int b = bid - 256;
        __shared__ float linv8[8];
        const int w = t >> 6, l = t & 63;
        #pragma unroll
        for (int hh = 0; hh < 2; ++hh) {
            const int h = w * 2 + hh;
            const u16* row = E + ((size_t)h * 512 + 256 + b) * 512;
            float s = 0.f;
            #pragma unroll
            for (int c = 0; c < 8; ++c) s += bf16_f32(row[c * 64 + l]);
            #pragma unroll
            for (int off = 32; off > 0; off >>= 1) s += __shfl_xor(s, off);
            if (l == 0) linv8[h] = 1.0f / s;
        }
        __syncthreads();
        #pragma unroll
        for (int mm_ = 0; mm_ < 2; ++mm_) {
            const int m = t + mm_ * 256;
            float s = 0.f;
            #pragma unroll
            for (int h = 0; h < H_; ++h)
                s += bf16_f32(E[((size_t)h * 512 + 256 + b) * 512 + m]) * linv8[h];
            wwb[(size_t)b * 512 + m] = s * 0.125f;
        }
    }
}

// ---------------------------------------------------------------------------
// L7 final (16432 blocks): [0,48) out-projection -> rd_out (hides under the
// write stream); [48,16432) memory update (403 MB, NT stores).
// ---------------------------------------------------------------------------
__global__ __launch_bounds__(256) void final_kernel(
    const u16* __restrict__ ctxb, const u16* __restrict__ outwb,
    const float* __restrict__ outb, float* __restrict__ rd_out,
    const float* __restrict__ mem, const float* __restrict__ wwb,
    const float* __restrict__ delta, float* __restrict__ mem_out)
{
    __shared__ u16 lA[4096], lB[4096];
    const int bid = blockIdx.x, t = threadIdx.x;
    if (bid < 48) {
        f32x4_t acc[4] = ACC_INIT;
        const int mt = bid / 12, nt = bid % 12;
        mm64b<64>(ctxb + (size_t)mt * 64 * 768, 768, outwb + (size_t)nt * 64 * 768, 768,
                  12, 63, lA, lB, acc, 4);
        epilogue_f32(acc, rd_out, 768, mt * 64, nt * 64, outb, 0, 4);
    } else {
        const int u = bid - 48;
        const int b  = u >> 6;            // 64 units per batch
        const int m0 = (u & 63) << 3;     // 8 rows per unit
        const f32x4_t* m4 = reinterpret_cast<const f32x4_t*>(mem);
        f32x4_t* o4 = reinterpret_cast<f32x4_t*>(mem_out + (size_t)b * 393216);
        const float* drow = delta + (size_t)b * 768;
        #pragma unroll
        for (int ph = 0; ph < 6; ++ph) {
            const int c = t + ph * 256;           // 0..1535 = 8 rows x 192 chunks
            const int m = m0 + c / 192;
            const int d4 = c % 192;
            const float w = wwb[(size_t)b * 512 + m];
            const f32x4_t dd = *reinterpret_cast<const f32x4_t*>(drow + d4 * 4);
            f32x4_t mm = m4[(size_t)m * 192 + d4];
            f32x4_t r = mm + w * dd;
            __builtin_nontemporal_store(r, &o4[(size_t)m * 192 + d4]);
        }
    }
}

// ---------------------------------------------------------------------------
extern "C" void kernel_launch(void* const* d_in, const int* in_sizes, int n_in,
                              void* d_out, int out_size, void* d_ws, size_t ws_size,
                              hipStream_t stream)
{
    const float* cs   = (const float*)d_in[0];
    const float* wdta = (const float*)d_in[1];
    const float* mem  = (const float*)d_in[2];
    const float* ipw  = (const float*)d_in[3];
    const float* ipb  = (const float*)d_in[4];
    const float* outw = (const float*)d_in[5];
    const float* outb = (const float*)d_in[6];
    const float* rw   = (const float*)d_in[7];
    const float* rb   = (const float*)d_in[8];
    const float* ww_w = (const float*)d_in[9];
    const float* ww_b = (const float*)d_in[10];
    const float* ew   = (const float*)d_in[11];
    const float* eb   = (const float*)d_in[12];
    const float* ugw  = (const float*)d_in[13];
    const float* ugb  = (const float*)d_in[14];
    const float* fgw  = (const float*)d_in[15];
    const float* fgb  = (const float*)d_in[16];

    float* rd_out  = (float*)d_out;              // read_data (B, D)
    float* mem_out = (float*)d_out + B_ * D_;    // updated_memory (B, M, D)

    // Scratch in mem_out region (dead until the final launch's update blocks;
    // the final launch reads ONLY inputs + d_ws). Offsets in f32 WORDS, %4==0.
    float* S0 = mem_out;
    u16*   memb    = (u16*)(S0 + 0);         // 512*768 bf16
    u16*   csb     = (u16*)(S0 + 196608);    // 256*768 bf16
    u16*   ipwb    = (u16*)(S0 + 294912);    // 2304*768 bf16
    u16*   rwb     = (u16*)(S0 + 1179648);   // 768*768 bf16
    u16*   wwwb    = (u16*)(S0 + 1474560);   // 768*768 bf16
    u16*   ewb     = (u16*)(S0 + 1769472);   // 768*768 bf16
    u16*   khb     = (u16*)(S0 + 2064384);   // 512*768 bf16
    u16*   vhT     = (u16*)(S0 + 2260992);   // 768*512 bf16
    u16*   rwkeysb = (u16*)(S0 + 2457600);   // 512*768 bf16
    u16*   qrwb    = (u16*)(S0 + 2654208);   // 512*768 bf16 (end 2850816 f)

    // d_ws (f32 words; all offsets %4==0). outwb lives HERE because the final
    // launch reads it while update overwrites mem_out.
    float* ws    = (float*)d_ws;
    float* erase = ws;                       // 196608 @ 0
    u16*   ctxb  = (u16*)(ws + 196608);      //  98304
    u16*   E     = (u16*)(ws + 294912);      // 1048576
    float* vg    =        ws + 1343488;      //   1536
    float* gc    =        ws + 1345024;      //     16
    float* delta =        ws + 1345040;      // 196608
    float* wwb   =        ws + 1541648;      // 131072
    u16*   outwb = (u16*)(ws + 1672720);     // 768*768 bf16 -> 294912 (end 1967632 f)

    conv_kernel<<<2328, 256, 0, stream>>>(mem, cs, ipw, rw, ww_w, ew, outw, outb,
                                          ugw, ugb, fgw, fgb,
                                          memb, csb, ipwb, rwb, wwwb, ewb, outwb,
                                          vg, gc);
    stage1_kernel<<<168, 256, 0, stream>>>(memb, csb, ipwb, ipb, rwb, rb, wwwb, ww_b,
                                           ewb, eb, khb, vhT, rwkeysb, erase);
    stage2_kernel<<<96, 256, 0, stream>>>(rwkeysb, ipwb, ipb, qrwb);
    scores_kernel<<<dim3(32, 8), 256, 0, stream>>>(qrwb, khb, E);
    pv_kernel<<<dim3(4, 2, 8), 256, 0, stream>>>(E, vhT, ctxb);
    gatesww_kernel<<<512, 256, 0, stream>>>(ctxb, cs, wdta, erase, ugw, fgw, vg, gc,
                                            E, delta, wwb);
    final_kernel<<<16432, 256, 0, stream>>>(ctxb, outwb, outb, rd_out,
                                            mem, wwb, delta, mem_out);
}

// Round 14
// 126.645 us; speedup vs baseline: 1.1265x; 1.1265x over previous
//
#include <hip/hip_runtime.h>
#include <hip/hip_bf16.h>
#include <math.h>

// Problem constants
#define B_ 256
#define M_ 512
#define D_ 768
#define H_ 8
#define DH_ 96
#define C_ 768

typedef float  f32x4_t __attribute__((ext_vector_type(4)));
typedef short  s16x8   __attribute__((ext_vector_type(8)));
typedef unsigned short u16;

__device__ __forceinline__ u16 cvt_bf16(float f) {
    __hip_bfloat16 h = __float2bfloat16(f);     // HW cvt path (RNE)
    union { __hip_bfloat16 h; u16 u; } v; v.h = h;
    return v.u;
}
__device__ __forceinline__ float bf16_f32(u16 h) {
    union { unsigned int u; float f; } v; v.u = ((unsigned int)h) << 16;
    return v.f;
}

#define ACC_INIT {{0,0,0,0},{0,0,0,0},{0,0,0,0},{0,0,0,0}}
#define SCALE_ 0.10206207261596577f   // 1/sqrt(96)

// ---------------------------------------------------------------------------
// 64x64 bf16 MFMA GEMM core (proven R5-R12), software-pipelined.
// tile = A(64xK) @ B(64xK)^T, both K-major bf16.
// ---------------------------------------------------------------------------
template<int BK>
__device__ __forceinline__ void mm64b(
    const u16* __restrict__ A, int lda, const u16* __restrict__ B, int ldb,
    int ksteps, int bRowClamp, u16* lA, u16* lB, f32x4_t* acc, int nfrag)
{
    constexpr int NL = BK / 32;
    const int t = threadIdx.x;
    const int srow = t >> 2, kq = t & 3;
    const int l = t & 63, w = t >> 6;
    const int brow = srow < bRowClamp ? srow : bRowClamp;

    s16x8 va[NL], vb[NL];
    #pragma unroll
    for (int c = 0; c < NL; ++c) {                 // preload k-step 0
        const int ko = (kq * NL + c) * 8;
        va[c] = *reinterpret_cast<const s16x8*>(A + (size_t)srow * lda + ko);
        vb[c] = *reinterpret_cast<const s16x8*>(B + (size_t)brow * ldb + ko);
    }

    for (int ks = 0; ks < ksteps; ++ks) {
        __syncthreads();                           // prev iter's frag reads done
        #pragma unroll
        for (int c = 0; c < NL; ++c) {
            const int kb = kq * NL + c;
            *reinterpret_cast<s16x8*>(lA + (kb * 64 + srow) * 8) = va[c];
            *reinterpret_cast<s16x8*>(lB + (kb * 64 + srow) * 8) = vb[c];
        }
        __syncthreads();
        if (ks + 1 < ksteps) {                     // prefetch: hides under MFMAs
            #pragma unroll
            for (int c = 0; c < NL; ++c) {
                const int ko = (ks + 1) * BK + (kq * NL + c) * 8;
                va[c] = *reinterpret_cast<const s16x8*>(A + (size_t)srow * lda + ko);
                vb[c] = *reinterpret_cast<const s16x8*>(B + (size_t)brow * ldb + ko);
            }
        }
        #pragma unroll
        for (int ksub = 0; ksub < NL; ++ksub) {
            const int kb = (l >> 4) + ksub * 4;
            s16x8 af = *reinterpret_cast<const s16x8*>(lA + (kb * 64 + w * 16 + (l & 15)) * 8);
            #pragma unroll
            for (int nb = 0; nb < 4; ++nb) {
                if (nb < nfrag) {
                    s16x8 bf = *reinterpret_cast<const s16x8*>(lB + (kb * 64 + nb * 16 + (l & 15)) * 8);
                    acc[nb] = __builtin_amdgcn_mfma_f32_16x16x32_bf16(af, bf, acc[nb], 0, 0, 0);
                }
            }
        }
    }
}

// C/D layout: col = lane&15, row = (lane>>4)*4 + reg (within wave's 16-row slice).
__device__ __forceinline__ void epilogue_f32(
    const f32x4_t* acc, float* out, int ldo, int m0, int n0,
    const float* bias, int act, int nfrag)
{
    const int t = threadIdx.x, l = t & 63, w = t >> 6;
    const int mbase = m0 + w * 16 + (l >> 4) * 4;
    #pragma unroll
    for (int nb = 0; nb < 4; ++nb) {
        if (nb >= nfrag) break;
        const int col = n0 + nb * 16 + (l & 15);
        const float bv = bias ? bias[col] : 0.0f;
        #pragma unroll
        for (int r = 0; r < 4; ++r) {
            float v = acc[nb][r] + bv;
            if (act) v = 1.0f / (1.0f + expf(-v));
            out[(size_t)(mbase + r) * ldo + col] = v;
        }
    }
}

__device__ __forceinline__ void epilogue_bf16(
    const f32x4_t* acc, u16* out, int ldo, int m0, int n0,
    const float* bias, int nfrag)
{
    const int t = threadIdx.x, l = t & 63, w = t >> 6;
    const int mbase = m0 + w * 16 + (l >> 4) * 4;
    #pragma unroll
    for (int nb = 0; nb < 4; ++nb) {
        if (nb >= nfrag) break;
        const int col = n0 + nb * 16 + (l & 15);
        const float bv = bias ? bias[col] : 0.0f;
        #pragma unroll
        for (int r = 0; r < 4; ++r)
            out[(size_t)(mbase + r) * ldo + col] = cvt_bf16(acc[nb][r] + bv);
    }
}

// ---------------------------------------------------------------------------
// L1 conv (2328 blocks): f32->bf16 conversions (2304) + vg/gc GEMV (24).
// ---------------------------------------------------------------------------
__global__ __launch_bounds__(256) void conv_kernel(
    const float* __restrict__ mem, const float* __restrict__ cs,
    const float* __restrict__ ipw, const float* __restrict__ rw,
    const float* __restrict__ www, const float* __restrict__ ew,
    const float* __restrict__ outw, const float* __restrict__ outb,
    const float* __restrict__ ugw, const float* __restrict__ ugb,
    const float* __restrict__ fgw, const float* __restrict__ fgb,
    u16* __restrict__ memb, u16* __restrict__ csb, u16* __restrict__ ipwb,
    u16* __restrict__ rwb, u16* __restrict__ wwwb, u16* __restrict__ ewb,
    u16* __restrict__ outwb, float* __restrict__ vg, float* __restrict__ gc)
{
    __shared__ float sred[256];
    const int bid = blockIdx.x, t = threadIdx.x;

    if (bid < 2304) {
        const float* src; u16* dst; int base;
        if      (bid < 192)  { src = mem;  dst = memb;  base = bid; }
        else if (bid < 288)  { src = cs;   dst = csb;   base = bid - 192; }
        else if (bid < 1152) { src = ipw;  dst = ipwb;  base = bid - 288; }
        else if (bid < 1440) { src = rw;   dst = rwb;   base = bid - 1152; }
        else if (bid < 1728) { src = www;  dst = wwwb;  base = bid - 1440; }
        else if (bid < 2016) { src = ew;   dst = ewb;   base = bid - 1728; }
        else                 { src = outw; dst = outwb; base = bid - 2016; }
        const size_t i = ((size_t)base * 256 + t) * 8;
        float4 x = *reinterpret_cast<const float4*>(src + i);
        float4 y = *reinterpret_cast<const float4*>(src + i + 4);
        s16x8 o;
        o[0]=cvt_bf16(x.x); o[1]=cvt_bf16(x.y); o[2]=cvt_bf16(x.z); o[3]=cvt_bf16(x.w);
        o[4]=cvt_bf16(y.x); o[5]=cvt_bf16(y.y); o[6]=cvt_bf16(y.z); o[7]=cvt_bf16(y.w);
        *reinterpret_cast<s16x8*>(dst + i) = o;
    } else {
        const int lid = bid - 2304;
        const int v = lid / 12, kt = lid % 12;
        const float* gw = v == 0 ? ugw : fgw;
        const int c = t & 63, g = t >> 6;
        const int col = kt * 64 + c;
        float acc = 0.f;
        #pragma unroll 4
        for (int i = 0; i < 192; ++i) {
            const int row = g * 192 + i;
            acc += outw[(size_t)row * 768 + col] * gw[768 + row];
        }
        sred[t] = acc;
        __syncthreads();
        if (g == 0)
            vg[v * 768 + col] = sred[c] + sred[64 + c] + sred[128 + c] + sred[192 + c];
        if (kt == 0) {
            __syncthreads();
            float cp = outb[t] * gw[768 + t] + outb[t + 256] * gw[768 + t + 256]
                     + outb[t + 512] * gw[768 + t + 512];
            sred[t] = cp; __syncthreads();
            #pragma unroll
            for (int off = 128; off > 0; off >>= 1) {
                if (t < off) sred[t] += sred[t + off];
                __syncthreads();
            }
            if (t == 0) gc[v] = sred[0] + (v == 0 ? ugb[0] : fgb[0]);
        }
    }
}

// ---------------------------------------------------------------------------
// L2 stage1 (336 blocks): kh+vhT (192), read keys (48), write keys (48), erase (48)
// ---------------------------------------------------------------------------
__global__ __launch_bounds__(256) void stage1_kernel(
    const u16* __restrict__ memb, const u16* __restrict__ csb,
    const u16* __restrict__ ipwb, const float* __restrict__ ipb,
    const u16* __restrict__ rwb, const float* __restrict__ rb,
    const u16* __restrict__ wwwb, const float* __restrict__ ww_b,
    const u16* __restrict__ ewb, const float* __restrict__ eb,
    u16* __restrict__ khb, u16* __restrict__ vhT,
    u16* __restrict__ rwkeysb, float* __restrict__ erase)
{
    __shared__ u16 lA[8192], lB[8192];
    f32x4_t acc[4] = ACC_INIT;
    const int bid = blockIdx.x;
    if (bid < 192) {
        const int mt = bid / 24, nt = bid % 24;
        mm64b<64>(memb + (size_t)mt * 64 * 768, 768,
                  ipwb + (size_t)768 * 768 + (size_t)nt * 64 * 768, 768,
                  12, 63, lA, lB, acc, 4);
        const int t = threadIdx.x, l = t & 63, w = t >> 6;
        const int mbase = mt * 64 + w * 16 + (l >> 4) * 4;
        if (nt < 12) {
            #pragma unroll
            for (int nb = 0; nb < 4; ++nb) {
                const int col = nt * 64 + nb * 16 + (l & 15);
                const float bv = ipb[768 + col];
                #pragma unroll
                for (int r = 0; r < 4; ++r)
                    khb[(size_t)(mbase + r) * 768 + col] = cvt_bf16(acc[nb][r] + bv);
            }
        } else {
            #pragma unroll
            for (int nb = 0; nb < 4; ++nb) {
                const int cg = (nt - 12) * 64 + nb * 16 + (l & 15);   // 0..767
                const int h = cg / 96, d = cg % 96;
                const float bv = ipb[1536 + cg];
                u16* dst = vhT + ((size_t)h * 96 + d) * 512;
                #pragma unroll
                for (int r = 0; r < 4; ++r)
                    dst[mbase + r] = cvt_bf16(acc[nb][r] + bv);
            }
        }
    } else if (bid < 240) {
        const int lid = bid - 192, mt = lid / 12, nt = lid % 12;
        mm64b<64>(csb + (size_t)mt * 64 * 768, 768, rwb + (size_t)nt * 64 * 768, 768,
                  12, 63, lA, lB, acc, 4);
        epilogue_bf16(acc, rwkeysb, 768, mt * 64, nt * 64, rb, 4);
    } else if (bid < 288) {
        const int lid = bid - 240, mt = lid / 12, nt = lid % 12;
        mm64b<64>(csb + (size_t)mt * 64 * 768, 768, wwwb + (size_t)nt * 64 * 768, 768,
                  12, 63, lA, lB, acc, 4);
        epilogue_bf16(acc, rwkeysb + (size_t)256 * 768, 768, mt * 64, nt * 64, ww_b, 4);
    } else {
        const int lid = bid - 288, mt = lid / 12, nt = lid % 12;
        mm64b<64>(csb + (size_t)mt * 64 * 768, 768, ewb + (size_t)nt * 64 * 768, 768,
                  12, 63, lA, lB, acc, 4);
        epilogue_f32(acc, erase, 768, mt * 64, nt * 64, eb, 1, 4);
    }
}

// ---------------------------------------------------------------------------
// L3 stage2 (96 blocks): qrw = rwkeys(512x768) @ wq^T + bq -> bf16
// ---------------------------------------------------------------------------
__global__ __launch_bounds__(256) void stage2_kernel(
    const u16* __restrict__ rwkeysb, const u16* __restrict__ ipwb,
    const float* __restrict__ ipb, u16* __restrict__ qrwb)
{
    __shared__ u16 lA[8192], lB[8192];
    f32x4_t acc[4] = ACC_INIT;
    const int mt = blockIdx.x / 12, nt = blockIdx.x % 12;
    mm64b<64>(rwkeysb + (size_t)mt * 64 * 768, 768, ipwb + (size_t)nt * 64 * 768, 768,
              12, 63, lA, lB, acc, 4);
    epilogue_bf16(acc, qrwb, 768, mt * 64, nt * 64, ipb, 4);
}

// ---------------------------------------------------------------------------
// L4 scores (grid (64,8)): E[h][q][m] = exp(min(q.k*scale,30)) bf16
// ---------------------------------------------------------------------------
__global__ __launch_bounds__(256) void scores_kernel(
    const u16* __restrict__ qrwb, const u16* __restrict__ khb, u16* __restrict__ E)
{
    __shared__ u16 lA[2048], lB[2048];
    f32x4_t acc[4] = ACC_INIT;
    const int h = blockIdx.y;
    const int mt = blockIdx.x >> 3, nt = blockIdx.x & 7;
    mm64b<32>(qrwb + (size_t)mt * 64 * 768 + h * 96, 768,
              khb + (size_t)nt * 64 * 768 + h * 96, 768, 3, 63, lA, lB, acc, 4);
    const int t = threadIdx.x, l = t & 63, w = t >> 6;
    const int mbase = mt * 64 + w * 16 + (l >> 4) * 4;     // q
    #pragma unroll
    for (int nb = 0; nb < 4; ++nb) {
        const int col = nt * 64 + nb * 16 + (l & 15);       // m
        #pragma unroll
        for (int r = 0; r < 4; ++r) {
            const float e = expf(fminf(acc[nb][r] * SCALE_, 30.0f));
            E[((size_t)h * 512 + mbase + r) * 512 + col] = cvt_bf16(e);
        }
    }
}

// ---------------------------------------------------------------------------
// L5 pv+ww (320 blocks): [0,64) PV (1D decode of old (4,2,8) grid);
// [64,320) ww per batch (depends only on E, rides this launch for free).
// ---------------------------------------------------------------------------
__global__ __launch_bounds__(256) void pvww_kernel(
    const u16* __restrict__ E, const u16* __restrict__ vhT, u16* __restrict__ ctxb,
    float* __restrict__ wwb)
{
    const int bid = blockIdx.x, t = threadIdx.x;
    if (bid < 64) {
        __shared__ u16 lA[8192], lB[8192];
        __shared__ float rinv[64];
        f32x4_t acc[4] = ACC_INIT;
        const int h = bid >> 3;
        const int mt = (bid >> 1) & 3, nt = bid & 1;
        const int n0 = nt * 64;
        const int nfrag = nt == 0 ? 4 : 2;
        const int bclamp = nt == 0 ? 63 : 31;

        const u16* A  = E + ((size_t)h * 512 + mt * 64) * 512;
        const u16* Bv = vhT + ((size_t)h * 96 + n0) * 512;

        const int srow = t >> 2, kq = t & 3;
        const int l = t & 63, w = t >> 6;
        const int brow = srow < bclamp ? srow : bclamp;

        s16x8 va[2], vb[2];
        #pragma unroll
        for (int c = 0; c < 2; ++c) {                  // preload ks=0
            const int ko = (kq * 2 + c) * 8;
            va[c] = *reinterpret_cast<const s16x8*>(A + (size_t)srow * 512 + ko);
            vb[c] = *reinterpret_cast<const s16x8*>(Bv + (size_t)brow * 512 + ko);
        }

        float rs = 0.f;
        for (int ks = 0; ks < 8; ++ks) {
            __syncthreads();
            #pragma unroll
            for (int c = 0; c < 2; ++c) {
                const int kb = kq * 2 + c;
                *reinterpret_cast<s16x8*>(lA + (kb * 64 + srow) * 8) = va[c];
                *reinterpret_cast<s16x8*>(lB + (kb * 64 + srow) * 8) = vb[c];
            }
            #pragma unroll
            for (int c = 0; c < 2; ++c)                // row-sum on staged values
                #pragma unroll
                for (int j = 0; j < 8; ++j)
                    rs += bf16_f32((u16)va[c][j]);
            __syncthreads();
            if (ks + 1 < 8) {                          // prefetch hides under MFMAs
                #pragma unroll
                for (int c = 0; c < 2; ++c) {
                    const int ko = (ks + 1) * 64 + (kq * 2 + c) * 8;
                    va[c] = *reinterpret_cast<const s16x8*>(A + (size_t)srow * 512 + ko);
                    vb[c] = *reinterpret_cast<const s16x8*>(Bv + (size_t)brow * 512 + ko);
                }
            }
            #pragma unroll
            for (int ksub = 0; ksub < 2; ++ksub) {
                const int kb = (l >> 4) + ksub * 4;
                s16x8 af = *reinterpret_cast<const s16x8*>(lA + (kb * 64 + w * 16 + (l & 15)) * 8);
                #pragma unroll
                for (int nb = 0; nb < 4; ++nb) {
                    if (nb < nfrag) {
                        s16x8 bf = *reinterpret_cast<const s16x8*>(lB + (kb * 64 + nb * 16 + (l & 15)) * 8);
                        acc[nb] = __builtin_amdgcn_mfma_f32_16x16x32_bf16(af, bf, acc[nb], 0, 0, 0);
                    }
                }
            }
        }
        rs += __shfl_xor(rs, 1);
        rs += __shfl_xor(rs, 2);
        if (kq == 0) rinv[srow] = 1.0f / rs;
        __syncthreads();

        const int mbase = w * 16 + (l >> 4) * 4;
        #pragma unroll
        for (int nb = 0; nb < 4; ++nb) {
            if (nb >= nfrag) break;
            const int col = n0 + nb * 16 + (l & 15);
            #pragma unroll
            for (int r = 0; r < 4; ++r) {
                const float v = acc[nb][r] * rinv[mbase + r];
                ctxb[(size_t)(mt * 64 + mbase + r) * 768 + h * 96 + col] = cvt_bf16(v);
            }
        }
    } else {
        // ww[b][m] = 0.125 * sum_h E[h][256+b][m] / rowsum(h, 256+b)
        const int b = bid - 64;
        __shared__ float linv8[8];
        const int w = t >> 6, l = t & 63;
        #pragma unroll
        for (int hh = 0; hh < 2; ++hh) {
            const int h = w * 2 + hh;
            const u16* row = E + ((size_t)h * 512 + 256 + b) * 512;
            float s = 0.f;
            #pragma unroll
            for (int c = 0; c < 8; ++c) s += bf16_f32(row[c * 64 + l]);
            #pragma unroll
            for (int off = 32; off > 0; off >>= 1) s += __shfl_xor(s, off);
            if (l == 0) linv8[h] = 1.0f / s;
        }
        __syncthreads();
        #pragma unroll
        for (int mm_ = 0; mm_ < 2; ++mm_) {
            const int m = t + mm_ * 256;
            float s = 0.f;
            #pragma unroll
            for (int h = 0; h < H_; ++h)
                s += bf16_f32(E[((size_t)h * 512 + 256 + b) * 512 + m]) * linv8[h];
            wwb[(size_t)b * 512 + m] = s * 0.125f;
        }
    }
}

// ---------------------------------------------------------------------------
// L6 gates (256 blocks): per-batch ug/fg scalars only (delta folded into L7).
// ---------------------------------------------------------------------------
__global__ __launch_bounds__(256) void gates_kernel(
    const u16* __restrict__ ctxb,
    const float* __restrict__ cs,
    const float* __restrict__ ugw, const float* __restrict__ fgw,
    const float* __restrict__ vg, const float* __restrict__ gc,
    float* __restrict__ ugfg)
{
    const int b = blockIdx.x, t = threadIdx.x;
    __shared__ float red[8];
    float pu = 0.f, pf = 0.f;
    #pragma unroll
    for (int c = 0; c < 3; ++c) {
        const int i = t + c * 256;
        const float cv = cs[(size_t)b * 768 + i];
        const float xv = bf16_f32(ctxb[(size_t)b * 768 + i]);
        pu += cv * ugw[i] + xv * vg[i];
        pf += cv * fgw[i] + xv * vg[768 + i];
    }
    const int w = t >> 6, l = t & 63;
    #pragma unroll
    for (int off = 32; off > 0; off >>= 1) {
        pu += __shfl_xor(pu, off);
        pf += __shfl_xor(pf, off);
    }
    if (l == 0) { red[w] = pu; red[4 + w] = pf; }
    __syncthreads();
    if (t == 0) {
        ugfg[2 * b]     = 1.0f / (1.0f + expf(-(red[0] + red[1] + red[2] + red[3] + gc[0])));
        ugfg[2 * b + 1] = 1.0f / (1.0f + expf(-(red[4] + red[5] + red[6] + red[7] + gc[1])));
    }
}

// ---------------------------------------------------------------------------
// L7 final (16432 blocks): [0,48) out-projection -> rd_out (hides under the
// write stream); [48,16432) memory update with INLINE delta:
//   out[b,m,d] = mem[m,d] + ww[b,m]*(wdta[b,d]*ug[b] - erase[b,d]*fg[b])
// Reads only inputs + d_ws (mem_out scratch is being overwritten).
// ---------------------------------------------------------------------------
__global__ __launch_bounds__(256) void final_kernel(
    const u16* __restrict__ ctxb, const u16* __restrict__ outwb,
    const float* __restrict__ outb, float* __restrict__ rd_out,
    const float* __restrict__ mem, const float* __restrict__ wwb,
    const float* __restrict__ wdta, const float* __restrict__ erase,
    const float* __restrict__ ugfg, float* __restrict__ mem_out)
{
    __shared__ u16 lA[8192], lB[8192];
    const int bid = blockIdx.x, t = threadIdx.x;
    if (bid < 48) {
        f32x4_t acc[4] = ACC_INIT;
        const int mt = bid / 12, nt = bid % 12;
        mm64b<64>(ctxb + (size_t)mt * 64 * 768, 768, outwb + (size_t)nt * 64 * 768, 768,
                  12, 63, lA, lB, acc, 4);
        epilogue_f32(acc, rd_out, 768, mt * 64, nt * 64, outb, 0, 4);
    } else {
        const int u = bid - 48;
        const int b  = u >> 6;            // 64 units per batch
        const int m0 = (u & 63) << 3;     // 8 rows per unit
        const float ug = ugfg[2 * b], fg = ugfg[2 * b + 1];
        const f32x4_t* m4 = reinterpret_cast<const f32x4_t*>(mem);
        f32x4_t* o4 = reinterpret_cast<f32x4_t*>(mem_out + (size_t)b * 393216);
        const float* wrow = wdta  + (size_t)b * 768;
        const float* erow = erase + (size_t)b * 768;
        #pragma unroll
        for (int ph = 0; ph < 6; ++ph) {
            const int c = t + ph * 256;           // 0..1535 = 8 rows x 192 chunks
            const int m = m0 + c / 192;
            const int d4 = c % 192;
            const float w = wwb[(size_t)b * 512 + m];
            const f32x4_t wd = *reinterpret_cast<const f32x4_t*>(wrow + d4 * 4);
            const f32x4_t er = *reinterpret_cast<const f32x4_t*>(erow + d4 * 4);
            const f32x4_t dd = wd * ug - er * fg;
            f32x4_t mm = m4[(size_t)m * 192 + d4];
            f32x4_t r = mm + w * dd;
            __builtin_nontemporal_store(r, &o4[(size_t)m * 192 + d4]);
        }
    }
}

// ---------------------------------------------------------------------------
extern "C" void kernel_launch(void* const* d_in, const int* in_sizes, int n_in,
                              void* d_out, int out_size, void* d_ws, size_t ws_size,
                              hipStream_t stream)
{
    const float* cs   = (const float*)d_in[0];
    const float* wdta = (const float*)d_in[1];
    const float* mem  = (const float*)d_in[2];
    const float* ipw  = (const float*)d_in[3];
    const float* ipb  = (const float*)d_in[4];
    const float* outw = (const float*)d_in[5];
    const float* outb = (const float*)d_in[6];
    const float* rw   = (const float*)d_in[7];
    const float* rb   = (const float*)d_in[8];
    const float* ww_w = (const float*)d_in[9];
    const float* ww_b = (const float*)d_in[10];
    const float* ew   = (const float*)d_in[11];
    const float* eb   = (const float*)d_in[12];
    const float* ugw  = (const float*)d_in[13];
    const float* ugb  = (const float*)d_in[14];
    const float* fgw  = (const float*)d_in[15];
    const float* fgb  = (const float*)d_in[16];

    float* rd_out  = (float*)d_out;              // read_data (B, D)
    float* mem_out = (float*)d_out + B_ * D_;    // updated_memory (B, M, D)

    // Scratch in mem_out region (dead until the final launch's update blocks;
    // the final launch reads ONLY inputs + d_ws). Offsets in f32 WORDS, %4==0.
    float* S0 = mem_out;
    u16*   memb    = (u16*)(S0 + 0);         // 512*768 bf16
    u16*   csb     = (u16*)(S0 + 196608);    // 256*768 bf16
    u16*   ipwb    = (u16*)(S0 + 294912);    // 2304*768 bf16
    u16*   rwb     = (u16*)(S0 + 1179648);   // 768*768 bf16
    u16*   wwwb    = (u16*)(S0 + 1474560);   // 768*768 bf16
    u16*   ewb     = (u16*)(S0 + 1769472);   // 768*768 bf16
    u16*   khb     = (u16*)(S0 + 2064384);   // 512*768 bf16
    u16*   vhT     = (u16*)(S0 + 2260992);   // 768*512 bf16
    u16*   rwkeysb = (u16*)(S0 + 2457600);   // 512*768 bf16
    u16*   qrwb    = (u16*)(S0 + 2654208);   // 512*768 bf16 (end 2850816 f)

    // d_ws (f32 words; all offsets %4==0). outwb/erase live HERE because the
    // final launch reads them while update overwrites mem_out.
    float* ws    = (float*)d_ws;
    float* erase = ws;                       // 196608 @ 0
    u16*   ctxb  = (u16*)(ws + 196608);      //  98304
    u16*   E     = (u16*)(ws + 294912);      // 1048576
    float* vg    =        ws + 1343488;      //   1536
    float* gc    =        ws + 1345024;      //     16
    float* ugfg  =        ws + 1345040;      //    512
    float* wwb   =        ws + 1345552;      // 131072
    u16*   outwb = (u16*)(ws + 1476624);     // 768*768 bf16 -> 294912 (end 1771536 f)

    conv_kernel<<<2328, 256, 0, stream>>>(mem, cs, ipw, rw, ww_w, ew, outw, outb,
                                          ugw, ugb, fgw, fgb,
                                          memb, csb, ipwb, rwb, wwwb, ewb, outwb,
                                          vg, gc);
    stage1_kernel<<<336, 256, 0, stream>>>(memb, csb, ipwb, ipb, rwb, rb, wwwb, ww_b,
                                           ewb, eb, khb, vhT, rwkeysb, erase);
    stage2_kernel<<<96, 256, 0, stream>>>(rwkeysb, ipwb, ipb, qrwb);
    scores_kernel<<<dim3(64, 8), 256, 0, stream>>>(qrwb, khb, E);
    pvww_kernel<<<320, 256, 0, stream>>>(E, vhT, ctxb, wwb);
    gates_kernel<<<256, 256, 0, stream>>>(ctxb, cs, ugw, fgw, vg, gc, ugfg);
    final_kernel<<<16432, 256, 0, stream>>>(ctxb, outwb, outb, rd_out,
                                            mem, wwb, wdta, erase, ugfg, mem_out);
}

// Round 15
// 124.781 us; speedup vs baseline: 1.1433x; 1.0149x over previous
//
#include <hip/hip_runtime.h>
#include <hip/hip_bf16.h>
#include <math.h>

// Problem constants
#define B_ 256
#define M_ 512
#define D_ 768
#define H_ 8
#define DH_ 96
#define C_ 768

typedef float  f32x4_t __attribute__((ext_vector_type(4)));
typedef short  s16x8   __attribute__((ext_vector_type(8)));
typedef unsigned short u16;

__device__ __forceinline__ u16 cvt_bf16(float f) {
    __hip_bfloat16 h = __float2bfloat16(f);     // HW cvt path (RNE)
    union { __hip_bfloat16 h; u16 u; } v; v.h = h;
    return v.u;
}
__device__ __forceinline__ float bf16_f32(u16 h) {
    union { unsigned int u; float f; } v; v.u = ((unsigned int)h) << 16;
    return v.f;
}

#define ACC_INIT {{0,0,0,0},{0,0,0,0},{0,0,0,0},{0,0,0,0}}
#define SCALE_ 0.10206207261596577f   // 1/sqrt(96)

// ---------------------------------------------------------------------------
// 64x64 bf16 MFMA GEMM core (proven R5-R14), software-pipelined.
// ---------------------------------------------------------------------------
template<int BK>
__device__ __forceinline__ void mm64b(
    const u16* __restrict__ A, int lda, const u16* __restrict__ B, int ldb,
    int ksteps, int bRowClamp, u16* lA, u16* lB, f32x4_t* acc, int nfrag)
{
    constexpr int NL = BK / 32;
    const int t = threadIdx.x;
    const int srow = t >> 2, kq = t & 3;
    const int l = t & 63, w = t >> 6;
    const int brow = srow < bRowClamp ? srow : bRowClamp;

    s16x8 va[NL], vb[NL];
    #pragma unroll
    for (int c = 0; c < NL; ++c) {                 // preload k-step 0
        const int ko = (kq * NL + c) * 8;
        va[c] = *reinterpret_cast<const s16x8*>(A + (size_t)srow * lda + ko);
        vb[c] = *reinterpret_cast<const s16x8*>(B + (size_t)brow * ldb + ko);
    }

    for (int ks = 0; ks < ksteps; ++ks) {
        __syncthreads();                           // prev iter's frag reads done
        #pragma unroll
        for (int c = 0; c < NL; ++c) {
            const int kb = kq * NL + c;
            *reinterpret_cast<s16x8*>(lA + (kb * 64 + srow) * 8) = va[c];
            *reinterpret_cast<s16x8*>(lB + (kb * 64 + srow) * 8) = vb[c];
        }
        __syncthreads();
        if (ks + 1 < ksteps) {                     // prefetch: hides under MFMAs
            #pragma unroll
            for (int c = 0; c < NL; ++c) {
                const int ko = (ks + 1) * BK + (kq * NL + c) * 8;
                va[c] = *reinterpret_cast<const s16x8*>(A + (size_t)srow * lda + ko);
                vb[c] = *reinterpret_cast<const s16x8*>(B + (size_t)brow * ldb + ko);
            }
        }
        #pragma unroll
        for (int ksub = 0; ksub < NL; ++ksub) {
            const int kb = (l >> 4) + ksub * 4;
            s16x8 af = *reinterpret_cast<const s16x8*>(lA + (kb * 64 + w * 16 + (l & 15)) * 8);
            #pragma unroll
            for (int nb = 0; nb < 4; ++nb) {
                if (nb < nfrag) {
                    s16x8 bf = *reinterpret_cast<const s16x8*>(lB + (kb * 64 + nb * 16 + (l & 15)) * 8);
                    acc[nb] = __builtin_amdgcn_mfma_f32_16x16x32_bf16(af, bf, acc[nb], 0, 0, 0);
                }
            }
        }
    }
}

// C/D layout: col = lane&15, row = (lane>>4)*4 + reg (within wave's 16-row slice).
__device__ __forceinline__ void epilogue_f32(
    const f32x4_t* acc, float* out, int ldo, int m0, int n0,
    const float* bias, int act, int nfrag)
{
    const int t = threadIdx.x, l = t & 63, w = t >> 6;
    const int mbase = m0 + w * 16 + (l >> 4) * 4;
    #pragma unroll
    for (int nb = 0; nb < 4; ++nb) {
        if (nb >= nfrag) break;
        const int col = n0 + nb * 16 + (l & 15);
        const float bv = bias ? bias[col] : 0.0f;
        #pragma unroll
        for (int r = 0; r < 4; ++r) {
            float v = acc[nb][r] + bv;
            if (act) v = 1.0f / (1.0f + expf(-v));
            out[(size_t)(mbase + r) * ldo + col] = v;
        }
    }
}

__device__ __forceinline__ void epilogue_bf16(
    const f32x4_t* acc, u16* out, int ldo, int m0, int n0,
    const float* bias, int nfrag)
{
    const int t = threadIdx.x, l = t & 63, w = t >> 6;
    const int mbase = m0 + w * 16 + (l >> 4) * 4;
    #pragma unroll
    for (int nb = 0; nb < 4; ++nb) {
        if (nb >= nfrag) break;
        const int col = n0 + nb * 16 + (l & 15);
        const float bv = bias ? bias[col] : 0.0f;
        #pragma unroll
        for (int r = 0; r < 4; ++r)
            out[(size_t)(mbase + r) * ldo + col] = cvt_bf16(acc[nb][r] + bv);
    }
}

// ---------------------------------------------------------------------------
// L1 conv (2328 blocks): f32->bf16 conversions (2304) + vg/gc GEMV (24).
// ---------------------------------------------------------------------------
__global__ __launch_bounds__(256) void conv_kernel(
    const float* __restrict__ mem, const float* __restrict__ cs,
    const float* __restrict__ ipw, const float* __restrict__ rw,
    const float* __restrict__ www, const float* __restrict__ ew,
    const float* __restrict__ outw, const float* __restrict__ outb,
    const float* __restrict__ ugw, const float* __restrict__ ugb,
    const float* __restrict__ fgw, const float* __restrict__ fgb,
    u16* __restrict__ memb, u16* __restrict__ csb, u16* __restrict__ ipwb,
    u16* __restrict__ rwb, u16* __restrict__ wwwb, u16* __restrict__ ewb,
    u16* __restrict__ outwb, float* __restrict__ vg, float* __restrict__ gc)
{
    __shared__ float sred[256];
    const int bid = blockIdx.x, t = threadIdx.x;

    if (bid < 2304) {
        const float* src; u16* dst; int base;
        if      (bid < 192)  { src = mem;  dst = memb;  base = bid; }
        else if (bid < 288)  { src = cs;   dst = csb;   base = bid - 192; }
        else if (bid < 1152) { src = ipw;  dst = ipwb;  base = bid - 288; }
        else if (bid < 1440) { src = rw;   dst = rwb;   base = bid - 1152; }
        else if (bid < 1728) { src = www;  dst = wwwb;  base = bid - 1440; }
        else if (bid < 2016) { src = ew;   dst = ewb;   base = bid - 1728; }
        else                 { src = outw; dst = outwb; base = bid - 2016; }
        const size_t i = ((size_t)base * 256 + t) * 8;
        float4 x = *reinterpret_cast<const float4*>(src + i);
        float4 y = *reinterpret_cast<const float4*>(src + i + 4);
        s16x8 o;
        o[0]=cvt_bf16(x.x); o[1]=cvt_bf16(x.y); o[2]=cvt_bf16(x.z); o[3]=cvt_bf16(x.w);
        o[4]=cvt_bf16(y.x); o[5]=cvt_bf16(y.y); o[6]=cvt_bf16(y.z); o[7]=cvt_bf16(y.w);
        *reinterpret_cast<s16x8*>(dst + i) = o;
    } else {
        const int lid = bid - 2304;
        const int v = lid / 12, kt = lid % 12;
        const float* gw = v == 0 ? ugw : fgw;
        const int c = t & 63, g = t >> 6;
        const int col = kt * 64 + c;
        float acc = 0.f;
        #pragma unroll 4
        for (int i = 0; i < 192; ++i) {
            const int row = g * 192 + i;
            acc += outw[(size_t)row * 768 + col] * gw[768 + row];
        }
        sred[t] = acc;
        __syncthreads();
        if (g == 0)
            vg[v * 768 + col] = sred[c] + sred[64 + c] + sred[128 + c] + sred[192 + c];
        if (kt == 0) {
            __syncthreads();
            float cp = outb[t] * gw[768 + t] + outb[t + 256] * gw[768 + t + 256]
                     + outb[t + 512] * gw[768 + t + 512];
            sred[t] = cp; __syncthreads();
            #pragma unroll
            for (int off = 128; off > 0; off >>= 1) {
                if (t < off) sred[t] += sred[t + off];
                __syncthreads();
            }
            if (t == 0) gc[v] = sred[0] + (v == 0 ? ugb[0] : fgb[0]);
        }
    }
}

// ---------------------------------------------------------------------------
// L2 stage1 (336 blocks): kh+vhT (192), read keys (48), write keys (48), erase (48)
// ---------------------------------------------------------------------------
__global__ __launch_bounds__(256) void stage1_kernel(
    const u16* __restrict__ memb, const u16* __restrict__ csb,
    const u16* __restrict__ ipwb, const float* __restrict__ ipb,
    const u16* __restrict__ rwb, const float* __restrict__ rb,
    const u16* __restrict__ wwwb, const float* __restrict__ ww_b,
    const u16* __restrict__ ewb, const float* __restrict__ eb,
    u16* __restrict__ khb, u16* __restrict__ vhT,
    u16* __restrict__ rwkeysb, float* __restrict__ erase)
{
    __shared__ u16 lA[8192], lB[8192];
    f32x4_t acc[4] = ACC_INIT;
    const int bid = blockIdx.x;
    if (bid < 192) {
        const int mt = bid / 24, nt = bid % 24;
        mm64b<64>(memb + (size_t)mt * 64 * 768, 768,
                  ipwb + (size_t)768 * 768 + (size_t)nt * 64 * 768, 768,
                  12, 63, lA, lB, acc, 4);
        const int t = threadIdx.x, l = t & 63, w = t >> 6;
        const int mbase = mt * 64 + w * 16 + (l >> 4) * 4;
        if (nt < 12) {
            #pragma unroll
            for (int nb = 0; nb < 4; ++nb) {
                const int col = nt * 64 + nb * 16 + (l & 15);
                const float bv = ipb[768 + col];
                #pragma unroll
                for (int r = 0; r < 4; ++r)
                    khb[(size_t)(mbase + r) * 768 + col] = cvt_bf16(acc[nb][r] + bv);
            }
        } else {
            #pragma unroll
            for (int nb = 0; nb < 4; ++nb) {
                const int cg = (nt - 12) * 64 + nb * 16 + (l & 15);   // 0..767
                const int h = cg / 96, d = cg % 96;
                const float bv = ipb[1536 + cg];
                u16* dst = vhT + ((size_t)h * 96 + d) * 512;
                #pragma unroll
                for (int r = 0; r < 4; ++r)
                    dst[mbase + r] = cvt_bf16(acc[nb][r] + bv);
            }
        }
    } else if (bid < 240) {
        const int lid = bid - 192, mt = lid / 12, nt = lid % 12;
        mm64b<64>(csb + (size_t)mt * 64 * 768, 768, rwb + (size_t)nt * 64 * 768, 768,
                  12, 63, lA, lB, acc, 4);
        epilogue_bf16(acc, rwkeysb, 768, mt * 64, nt * 64, rb, 4);
    } else if (bid < 288) {
        const int lid = bid - 240, mt = lid / 12, nt = lid % 12;
        mm64b<64>(csb + (size_t)mt * 64 * 768, 768, wwwb + (size_t)nt * 64 * 768, 768,
                  12, 63, lA, lB, acc, 4);
        epilogue_bf16(acc, rwkeysb + (size_t)256 * 768, 768, mt * 64, nt * 64, ww_b, 4);
    } else {
        const int lid = bid - 288, mt = lid / 12, nt = lid % 12;
        mm64b<64>(csb + (size_t)mt * 64 * 768, 768, ewb + (size_t)nt * 64 * 768, 768,
                  12, 63, lA, lB, acc, 4);
        epilogue_f32(acc, erase, 768, mt * 64, nt * 64, eb, 1, 4);
    }
}

// ---------------------------------------------------------------------------
// L3 stage2+zv (112 blocks): [0,96) qrw GEMM; [96,112) zv[v][h][m] =
// sum_d vhT[h][d][m]*vg[v][h*96+d]  (gates pre-reduction over V).
// ---------------------------------------------------------------------------
__global__ __launch_bounds__(256) void stage2_kernel(
    const u16* __restrict__ rwkeysb, const u16* __restrict__ ipwb,
    const float* __restrict__ ipb, u16* __restrict__ qrwb,
    const u16* __restrict__ vhT, const float* __restrict__ vg,
    float* __restrict__ zv)
{
    const int bid = blockIdx.x, t = threadIdx.x;
    if (bid < 96) {
        __shared__ u16 lA[8192], lB[8192];
        f32x4_t acc[4] = ACC_INIT;
        const int mt = bid / 12, nt = bid % 12;
        mm64b<64>(rwkeysb + (size_t)mt * 64 * 768, 768, ipwb + (size_t)nt * 64 * 768, 768,
                  12, 63, lA, lB, acc, 4);
        epilogue_bf16(acc, qrwb, 768, mt * 64, nt * 64, ipb, 4);
    } else {
        const int lid = bid - 96;
        const int v = lid >> 3, h = lid & 7;
        float a0 = 0.f, a1 = 0.f;
        for (int d = 0; d < 96; ++d) {
            const float g = vg[v * 768 + h * 96 + d];
            const u16* row = vhT + ((size_t)h * 96 + d) * 512;
            a0 += bf16_f32(row[t]) * g;
            a1 += bf16_f32(row[t + 256]) * g;
        }
        zv[(size_t)v * 4096 + h * 512 + t]       = a0;
        zv[(size_t)v * 4096 + h * 512 + t + 256] = a1;
    }
}

// ---------------------------------------------------------------------------
// L4 scores (grid (64,8)): E[h][q][m] = exp(min(q.k*scale,30)) bf16
// ---------------------------------------------------------------------------
__global__ __launch_bounds__(256) void scores_kernel(
    const u16* __restrict__ qrwb, const u16* __restrict__ khb, u16* __restrict__ E)
{
    __shared__ u16 lA[2048], lB[2048];
    f32x4_t acc[4] = ACC_INIT;
    const int h = blockIdx.y;
    const int mt = blockIdx.x >> 3, nt = blockIdx.x & 7;
    mm64b<32>(qrwb + (size_t)mt * 64 * 768 + h * 96, 768,
              khb + (size_t)nt * 64 * 768 + h * 96, 768, 3, 63, lA, lB, acc, 4);
    const int t = threadIdx.x, l = t & 63, w = t >> 6;
    const int mbase = mt * 64 + w * 16 + (l >> 4) * 4;     // q
    #pragma unroll
    for (int nb = 0; nb < 4; ++nb) {
        const int col = nt * 64 + nb * 16 + (l & 15);       // m
        #pragma unroll
        for (int r = 0; r < 4; ++r) {
            const float e = expf(fminf(acc[nb][r] * SCALE_, 30.0f));
            E[((size_t)h * 512 + mbase + r) * 512 + col] = cvt_bf16(e);
        }
    }
}

// ---------------------------------------------------------------------------
// L5 pv+ww+gates (576 blocks): [0,64) PV; [64,320) ww per batch;
// [320,576) gates per batch via zv reordering:
//   ctx.vg == sum_h linv[h][b] * sum_m E[h][b][m]*zv[v][h][m]
// ---------------------------------------------------------------------------
__global__ __launch_bounds__(256) void pvww_kernel(
    const u16* __restrict__ E, const u16* __restrict__ vhT, u16* __restrict__ ctxb,
    float* __restrict__ wwb,
    const float* __restrict__ cs, const float* __restrict__ ugw,
    const float* __restrict__ fgw, const float* __restrict__ zv,
    const float* __restrict__ gc, float* __restrict__ ugfg)
{
    const int bid = blockIdx.x, t = threadIdx.x;
    if (bid < 64) {
        __shared__ u16 lA[8192], lB[8192];
        __shared__ float rinv[64];
        f32x4_t acc[4] = ACC_INIT;
        const int h = bid >> 3;
        const int mt = (bid >> 1) & 3, nt = bid & 1;
        const int n0 = nt * 64;
        const int nfrag = nt == 0 ? 4 : 2;
        const int bclamp = nt == 0 ? 63 : 31;

        const u16* A  = E + ((size_t)h * 512 + mt * 64) * 512;
        const u16* Bv = vhT + ((size_t)h * 96 + n0) * 512;

        const int srow = t >> 2, kq = t & 3;
        const int l = t & 63, w = t >> 6;
        const int brow = srow < bclamp ? srow : bclamp;

        s16x8 va[2], vb[2];
        #pragma unroll
        for (int c = 0; c < 2; ++c) {                  // preload ks=0
            const int ko = (kq * 2 + c) * 8;
            va[c] = *reinterpret_cast<const s16x8*>(A + (size_t)srow * 512 + ko);
            vb[c] = *reinterpret_cast<const s16x8*>(Bv + (size_t)brow * 512 + ko);
        }

        float rs = 0.f;
        for (int ks = 0; ks < 8; ++ks) {
            __syncthreads();
            #pragma unroll
            for (int c = 0; c < 2; ++c) {
                const int kb = kq * 2 + c;
                *reinterpret_cast<s16x8*>(lA + (kb * 64 + srow) * 8) = va[c];
                *reinterpret_cast<s16x8*>(lB + (kb * 64 + srow) * 8) = vb[c];
            }
            #pragma unroll
            for (int c = 0; c < 2; ++c)                // row-sum on staged values
                #pragma unroll
                for (int j = 0; j < 8; ++j)
                    rs += bf16_f32((u16)va[c][j]);
            __syncthreads();
            if (ks + 1 < 8) {                          // prefetch hides under MFMAs
                #pragma unroll
                for (int c = 0; c < 2; ++c) {
                    const int ko = (ks + 1) * 64 + (kq * 2 + c) * 8;
                    va[c] = *reinterpret_cast<const s16x8*>(A + (size_t)srow * 512 + ko);
                    vb[c] = *reinterpret_cast<const s16x8*>(Bv + (size_t)brow * 512 + ko);
                }
            }
            #pragma unroll
            for (int ksub = 0; ksub < 2; ++ksub) {
                const int kb = (l >> 4) + ksub * 4;
                s16x8 af = *reinterpret_cast<const s16x8*>(lA + (kb * 64 + w * 16 + (l & 15)) * 8);
                #pragma unroll
                for (int nb = 0; nb < 4; ++nb) {
                    if (nb < nfrag) {
                        s16x8 bf = *reinterpret_cast<const s16x8*>(lB + (kb * 64 + nb * 16 + (l & 15)) * 8);
                        acc[nb] = __builtin_amdgcn_mfma_f32_16x16x32_bf16(af, bf, acc[nb], 0, 0, 0);
                    }
                }
            }
        }
        rs += __shfl_xor(rs, 1);
        rs += __shfl_xor(rs, 2);
        if (kq == 0) rinv[srow] = 1.0f / rs;
        __syncthreads();

        const int mbase = w * 16 + (l >> 4) * 4;
        #pragma unroll
        for (int nb = 0; nb < 4; ++nb) {
            if (nb >= nfrag) break;
            const int col = n0 + nb * 16 + (l & 15);
            #pragma unroll
            for (int r = 0; r < 4; ++r) {
                const float v = acc[nb][r] * rinv[mbase + r];
                ctxb[(size_t)(mt * 64 + mbase + r) * 768 + h * 96 + col] = cvt_bf16(v);
            }
        }
    } else if (bid < 320) {
        // ww[b][m] = 0.125 * sum_h E[h][256+b][m] / rowsum(h, 256+b)
        const int b = bid - 64;
        __shared__ float linv8[8];
        const int w = t >> 6, l = t & 63;
        #pragma unroll
        for (int hh = 0; hh < 2; ++hh) {
            const int h = w * 2 + hh;
            const u16* row = E + ((size_t)h * 512 + 256 + b) * 512;
            float s = 0.f;
            #pragma unroll
            for (int c = 0; c < 8; ++c) s += bf16_f32(row[c * 64 + l]);
            #pragma unroll
            for (int off = 32; off > 0; off >>= 1) s += __shfl_xor(s, off);
            if (l == 0) linv8[h] = 1.0f / s;
        }
        __syncthreads();
        #pragma unroll
        for (int mm_ = 0; mm_ < 2; ++mm_) {
            const int m = t + mm_ * 256;
            float s = 0.f;
            #pragma unroll
            for (int h = 0; h < H_; ++h)
                s += bf16_f32(E[((size_t)h * 512 + 256 + b) * 512 + m]) * linv8[h];
            wwb[(size_t)b * 512 + m] = s * 0.125f;
        }
    } else {
        // gates: pu = cs.ugw + sum_h (sum_m E*zvu)/(sum_m E);  same for fg.
        const int b = bid - 320;
        __shared__ float wred[4][3];
        __shared__ float gacc[2];
        __shared__ float red[8];
        const int w = t >> 6, l = t & 63;
        if (t == 0) { gacc[0] = 0.f; gacc[1] = 0.f; }

        float pu = 0.f, pf = 0.f;                      // cs part
        #pragma unroll
        for (int c = 0; c < 3; ++c) {
            const int i = t + c * 256;
            const float cv = cs[(size_t)b * 768 + i];
            pu += cv * ugw[i];
            pf += cv * fgw[i];
        }

        for (int h = 0; h < 8; ++h) {                  // E-weighted part
            float s0 = 0.f, su = 0.f, sf = 0.f;
            #pragma unroll
            for (int mm_ = 0; mm_ < 2; ++mm_) {
                const int m = t + mm_ * 256;
                const float e = bf16_f32(E[((size_t)h * 512 + b) * 512 + m]);
                s0 += e;
                su += e * zv[(size_t)h * 512 + m];
                sf += e * zv[4096 + (size_t)h * 512 + m];
            }
            #pragma unroll
            for (int off = 32; off > 0; off >>= 1) {
                s0 += __shfl_xor(s0, off);
                su += __shfl_xor(su, off);
                sf += __shfl_xor(sf, off);
            }
            if (l == 0) { wred[w][0] = s0; wred[w][1] = su; wred[w][2] = sf; }
            __syncthreads();
            if (t == 0) {
                const float S0 = wred[0][0] + wred[1][0] + wred[2][0] + wred[3][0];
                const float Su = wred[0][1] + wred[1][1] + wred[2][1] + wred[3][1];
                const float Sf = wred[0][2] + wred[1][2] + wred[2][2] + wred[3][2];
                gacc[0] += Su / S0;
                gacc[1] += Sf / S0;
            }
            __syncthreads();
        }

        #pragma unroll
        for (int off = 32; off > 0; off >>= 1) {
            pu += __shfl_xor(pu, off);
            pf += __shfl_xor(pf, off);
        }
        if (l == 0) { red[w] = pu; red[4 + w] = pf; }
        __syncthreads();
        if (t == 0) {
            const float tu = red[0] + red[1] + red[2] + red[3] + gacc[0] + gc[0];
            const float tf = red[4] + red[5] + red[6] + red[7] + gacc[1] + gc[1];
            ugfg[2 * b]     = 1.0f / (1.0f + expf(-tu));
            ugfg[2 * b + 1] = 1.0f / (1.0f + expf(-tf));
        }
    }
}

// ---------------------------------------------------------------------------
// L6 final (16432 blocks): [0,48) out-projection -> rd_out (hides under the
// write stream); [48,16432) memory update with INLINE delta:
//   out[b,m,d] = mem[m,d] + ww[b,m]*(wdta[b,d]*ug[b] - erase[b,d]*fg[b])
// ---------------------------------------------------------------------------
__global__ __launch_bounds__(256) void final_kernel(
    const u16* __restrict__ ctxb, const u16* __restrict__ outwb,
    const float* __restrict__ outb, float* __restrict__ rd_out,
    const float* __restrict__ mem, const float* __restrict__ wwb,
    const float* __restrict__ wdta, const float* __restrict__ erase,
    const float* __restrict__ ugfg, float* __restrict__ mem_out)
{
    __shared__ u16 lA[8192], lB[8192];
    const int bid = blockIdx.x, t = threadIdx.x;
    if (bid < 48) {
        f32x4_t acc[4] = ACC_INIT;
        const int mt = bid / 12, nt = bid % 12;
        mm64b<64>(ctxb + (size_t)mt * 64 * 768, 768, outwb + (size_t)nt * 64 * 768, 768,
                  12, 63, lA, lB, acc, 4);
        epilogue_f32(acc, rd_out, 768, mt * 64, nt * 64, outb, 0, 4);
    } else {
        const int u = bid - 48;
        const int b  = u >> 6;            // 64 units per batch
        const int m0 = (u & 63) << 3;     // 8 rows per unit
        const float ug = ugfg[2 * b], fg = ugfg[2 * b + 1];
        const f32x4_t* m4 = reinterpret_cast<const f32x4_t*>(mem);
        f32x4_t* o4 = reinterpret_cast<f32x4_t*>(mem_out + (size_t)b * 393216);
        const float* wrow = wdta  + (size_t)b * 768;
        const float* erow = erase + (size_t)b * 768;
        #pragma unroll
        for (int ph = 0; ph < 6; ++ph) {
            const int c = t + ph * 256;           // 0..1535 = 8 rows x 192 chunks
            const int m = m0 + c / 192;
            const int d4 = c % 192;
            const float w = wwb[(size_t)b * 512 + m];
            const f32x4_t wd = *reinterpret_cast<const f32x4_t*>(wrow + d4 * 4);
            const f32x4_t er = *reinterpret_cast<const f32x4_t*>(erow + d4 * 4);
            const f32x4_t dd = wd * ug - er * fg;
            f32x4_t mm = m4[(size_t)m * 192 + d4];
            f32x4_t r = mm + w * dd;
            __builtin_nontemporal_store(r, &o4[(size_t)m * 192 + d4]);
        }
    }
}

// ---------------------------------------------------------------------------
extern "C" void kernel_launch(void* const* d_in, const int* in_sizes, int n_in,
                              void* d_out, int out_size, void* d_ws, size_t ws_size,
                              hipStream_t stream)
{
    const float* cs   = (const float*)d_in[0];
    const float* wdta = (const float*)d_in[1];
    const float* mem  = (const float*)d_in[2];
    const float* ipw  = (const float*)d_in[3];
    const float* ipb  = (const float*)d_in[4];
    const float* outw = (const float*)d_in[5];
    const float* outb = (const float*)d_in[6];
    const float* rw   = (const float*)d_in[7];
    const float* rb   = (const float*)d_in[8];
    const float* ww_w = (const float*)d_in[9];
    const float* ww_b = (const float*)d_in[10];
    const float* ew   = (const float*)d_in[11];
    const float* eb   = (const float*)d_in[12];
    const float* ugw  = (const float*)d_in[13];
    const float* ugb  = (const float*)d_in[14];
    const float* fgw  = (const float*)d_in[15];
    const float* fgb  = (const float*)d_in[16];

    float* rd_out  = (float*)d_out;              // read_data (B, D)
    float* mem_out = (float*)d_out + B_ * D_;    // updated_memory (B, M, D)

    // Scratch in mem_out region (dead until the final launch's update blocks;
    // the final launch reads ONLY inputs + d_ws). Offsets in f32 WORDS, %4==0.
    float* S0 = mem_out;
    u16*   memb    = (u16*)(S0 + 0);         // 512*768 bf16
    u16*   csb     = (u16*)(S0 + 196608);    // 256*768 bf16
    u16*   ipwb    = (u16*)(S0 + 294912);    // 2304*768 bf16
    u16*   rwb     = (u16*)(S0 + 1179648);   // 768*768 bf16
    u16*   wwwb    = (u16*)(S0 + 1474560);   // 768*768 bf16
    u16*   ewb     = (u16*)(S0 + 1769472);   // 768*768 bf16
    u16*   khb     = (u16*)(S0 + 2064384);   // 512*768 bf16
    u16*   vhT     = (u16*)(S0 + 2260992);   // 768*512 bf16
    u16*   rwkeysb = (u16*)(S0 + 2457600);   // 512*768 bf16
    u16*   qrwb    = (u16*)(S0 + 2654208);   // 512*768 bf16 (end 2850816 f)

    // d_ws (f32 words; all offsets %4==0). outwb/erase/zv live HERE because
    // the final launch reads outwb/erase while update overwrites mem_out.
    float* ws    = (float*)d_ws;
    float* erase = ws;                       // 196608 @ 0
    u16*   ctxb  = (u16*)(ws + 196608);      //  98304
    u16*   E     = (u16*)(ws + 294912);      // 1048576
    float* vg    =        ws + 1343488;      //   1536
    float* gc    =        ws + 1345024;      //     16
    float* ugfg  =        ws + 1345040;      //    512
    float* wwb   =        ws + 1345552;      // 131072
    u16*   outwb = (u16*)(ws + 1476624);     // 294912
    float* zv    =        ws + 1771536;      //   8192 (2 x 8 x 512; end 1779728 f)

    conv_kernel<<<2328, 256, 0, stream>>>(mem, cs, ipw, rw, ww_w, ew, outw, outb,
                                          ugw, ugb, fgw, fgb,
                                          memb, csb, ipwb, rwb, wwwb, ewb, outwb,
                                          vg, gc);
    stage1_kernel<<<336, 256, 0, stream>>>(memb, csb, ipwb, ipb, rwb, rb, wwwb, ww_b,
                                           ewb, eb, khb, vhT, rwkeysb, erase);
    stage2_kernel<<<112, 256, 0, stream>>>(rwkeysb, ipwb, ipb, qrwb, vhT, vg, zv);
    scores_kernel<<<dim3(64, 8), 256, 0, stream>>>(qrwb, khb, E);
    pvww_kernel<<<576, 256, 0, stream>>>(E, vhT, ctxb, wwb,
                                         cs, ugw, fgw, zv, gc, ugfg);
    final_kernel<<<16432, 256, 0, stream>>>(ctxb, outwb, outb, rd_out,
                                            mem, wwb, wdta, erase, ugfg, mem_out);
}